// Round 2
// baseline (343.513 us; speedup 1.0000x reference)
//
#include <hip/hip_runtime.h>
#include <hip/hip_bf16.h>
#include <stdint.h>

typedef __attribute__((ext_vector_type(4))) float f32x4;
typedef __attribute__((ext_vector_type(8))) __bf16 bf16x8;
typedef __attribute__((ext_vector_type(4))) unsigned int u32x4;

#define N_NODES 16384
#define F_DIM   64

__device__ inline unsigned cvtpk_bf16(float lo, float hi) {
    unsigned r;
    asm("v_cvt_pk_bf16_f32 %0, %1, %2" : "=v"(r) : "v"(lo), "v"(hi));
    return r;
}

// pack 8 consecutive fp32 (two f32x4) into one bf16x8 MFMA fragment
__device__ inline bf16x8 pack8(const f32x4 a, const f32x4 b) {
    union { u32x4 u; bf16x8 h; } cv;
    cv.u = (u32x4){cvtpk_bf16(a.x, a.y), cvtpk_bf16(a.z, a.w),
                   cvtpk_bf16(b.x, b.y), cvtpk_bf16(b.z, b.w)};
    return cv.h;
}

// ---------------------------------------------------------------------------
// Kernel A: h = input @ W (fp32 compute), stored bf16 in MFMA B-frag layout:
// chunk[(kb*4+ct)*64 + l] (16B) = h[kb*32 + (l>>4)*8 + j][ct*16 + (l&15)]
// ---------------------------------------------------------------------------
__global__ __launch_bounds__(256) void dense_h(const float* __restrict__ inp,
                                               const float* __restrict__ W,
                                               short* __restrict__ hpack) {
    __shared__ float in_lds[64][64];
    __shared__ float wt_lds[64][68];
    const int t = threadIdx.x;
    const int blk = blockIdx.x;

#pragma unroll
    for (int i = 0; i < 4; ++i) {
        int n = i * 256 + t; int row = n >> 4; int c = n & 15;
        f32x4 v = *(const f32x4*)(inp + (size_t)(blk * 64 + row) * 64 + c * 4);
        *(f32x4*)(&in_lds[row][c * 4]) = v;
    }
#pragma unroll
    for (int i = 0; i < 4; ++i) {
        int n = i * 256 + t; int k = n >> 4; int c = n & 15;
        f32x4 v = *(const f32x4*)(W + k * 64 + c * 4);
        wt_lds[c * 4 + 0][k] = v.x; wt_lds[c * 4 + 1][k] = v.y;
        wt_lds[c * 4 + 2][k] = v.z; wt_lds[c * 4 + 3][k] = v.w;
    }
    __syncthreads();

#pragma unroll
    for (int cc = 0; cc < 2; ++cc) {
        int c = cc * 256 + t;
        int kbL = c >> 8; int ct = (c >> 6) & 3; int l = c & 63;
        int f  = ct * 16 + (l & 15);
        int r0 = kbL * 32 + (l >> 4) * 8;
        float acc[8] = {0, 0, 0, 0, 0, 0, 0, 0};
        for (int k = 0; k < 64; k += 4) {
            f32x4 wv = *(const f32x4*)(&wt_lds[f][k]);
#pragma unroll
            for (int j = 0; j < 8; ++j) {
                f32x4 iv = *(const f32x4*)(&in_lds[r0 + j][k]);
                acc[j] += iv.x * wv.x + iv.y * wv.y + iv.z * wv.z + iv.w * wv.w;
            }
        }
        u32x4 w4 = {cvtpk_bf16(acc[0], acc[1]), cvtpk_bf16(acc[2], acc[3]),
                    cvtpk_bf16(acc[4], acc[5]), cvtpk_bf16(acc[6], acc[7])};
        int kb = blk * 2 + kbL;
        *(u32x4*)(hpack + ((size_t)(kb * 4 + ct) * 64 + l) * 8) = w4;
    }
}

// ---------------------------------------------------------------------------
// Kernel B: partial[sp] = adj[:, k-range] @ h[k-range, :]
// Fully wave-independent: no LDS, no barrier. Each wave owns 16 rows x 64 cols.
// A (adj fp32->bf16 via cvt_pk) and B (hp, L2-hot) double-buffered in regs,
// prefetched one iteration ahead -> all waits are counted vmcnt, never 0.
// ---------------------------------------------------------------------------
__global__ __launch_bounds__(256) void spmm_adj(const float* __restrict__ adj,
                                                const short* __restrict__ hp,
                                                float* __restrict__ out,
                                                int kspan) {
    const int rb = blockIdx.x;
    const int sp = blockIdx.y;
    const int k0 = sp * kspan;
    const int iters = kspan >> 6;          // K-step = 64
    const int t  = threadIdx.x;
    const int wv = t >> 6;
    const int ln = t & 63;

    const int arow = rb * 64 + wv * 16 + (ln & 15);
    const int kc   = (ln >> 4) * 8;        // fp32 offset of this lane's 8-elem chunk

    const float* pA = adj + (size_t)arow * N_NODES + k0 + kc;
    const short* pB = hp + (size_t)(k0 >> 5) * 2048 + ln * 8;

    auto ldA = [&](int tt, f32x4& x0, f32x4& x1, f32x4& x2, f32x4& x3) {
        const float* p = pA + (size_t)tt * 64;
        x0 = __builtin_nontemporal_load((const f32x4*)(p));
        x1 = __builtin_nontemporal_load((const f32x4*)(p + 4));
        x2 = __builtin_nontemporal_load((const f32x4*)(p + 32));
        x3 = __builtin_nontemporal_load((const f32x4*)(p + 36));
    };
    auto ldB = [&](int tt, bf16x8* b) {
        const short* h = pB + (size_t)tt * 4096;
#pragma unroll
        for (int ks2 = 0; ks2 < 2; ++ks2)
#pragma unroll
            for (int ct = 0; ct < 4; ++ct)
                b[ks2 * 4 + ct] = *(const bf16x8*)(h + ks2 * 2048 + ct * 512);
    };

    f32x4 acc[4] = {{0,0,0,0},{0,0,0,0},{0,0,0,0},{0,0,0,0}};
    f32x4 aC0, aC1, aC2, aC3, aN0, aN1, aN2, aN3;
    bf16x8 bC[8], bN[8];

    ldB(0, bC);
    ldA(0, aC0, aC1, aC2, aC3);

    for (int tt = 0; tt < iters; tt += 2) {
        // prefetch iter tt+1 (stays in flight across consume of tt: counted vmcnt)
        ldB(tt + 1, bN);
        ldA(tt + 1, aN0, aN1, aN2, aN3);
        {
            bf16x8 af0 = pack8(aC0, aC1);
            bf16x8 af1 = pack8(aC2, aC3);
#pragma unroll
            for (int ct = 0; ct < 4; ++ct)
                acc[ct] = __builtin_amdgcn_mfma_f32_16x16x32_bf16(af0, bC[ct], acc[ct], 0, 0, 0);
#pragma unroll
            for (int ct = 0; ct < 4; ++ct)
                acc[ct] = __builtin_amdgcn_mfma_f32_16x16x32_bf16(af1, bC[4 + ct], acc[ct], 0, 0, 0);
        }
        if (tt + 2 < iters) {               // uniform branch; last iter skips prefetch
            ldB(tt + 2, bC);
            ldA(tt + 2, aC0, aC1, aC2, aC3);
        }
        {
            bf16x8 af0 = pack8(aN0, aN1);
            bf16x8 af1 = pack8(aN2, aN3);
#pragma unroll
            for (int ct = 0; ct < 4; ++ct)
                acc[ct] = __builtin_amdgcn_mfma_f32_16x16x32_bf16(af0, bN[ct], acc[ct], 0, 0, 0);
#pragma unroll
            for (int ct = 0; ct < 4; ++ct)
                acc[ct] = __builtin_amdgcn_mfma_f32_16x16x32_bf16(af1, bN[4 + ct], acc[ct], 0, 0, 0);
        }
    }

    // epilogue: C layout col=lane&15, row=(lane>>4)*4+j
    float* o = out + (size_t)sp * ((size_t)N_NODES * F_DIM);
    const int orow0 = rb * 64 + wv * 16 + (ln >> 4) * 4;
    const int col   = ln & 15;
#pragma unroll
    for (int ct = 0; ct < 4; ++ct)
#pragma unroll
        for (int j = 0; j < 4; ++j)
            o[(size_t)(orow0 + j) * F_DIM + ct * 16 + col] = acc[ct][j];
}

// ---------------------------------------------------------------------------
// Kernel C: out = sum_i partial[i] + bias
// ---------------------------------------------------------------------------
__global__ __launch_bounds__(256) void reduce_add(const float* __restrict__ part,
                                                  const float* __restrict__ bias,
                                                  float* __restrict__ out, int nsp) {
    int g = blockIdx.x * 256 + threadIdx.x;
    f32x4 s = {0, 0, 0, 0};
    for (int i = 0; i < nsp; ++i)
        s += *(const f32x4*)(part + (size_t)i * ((size_t)N_NODES * F_DIM) + (size_t)g * 4);
    f32x4 bv = *(const f32x4*)(bias + ((g * 4) & 63));
    *(f32x4*)(out + (size_t)g * 4) = s + bv;
}

extern "C" void kernel_launch(void* const* d_in, const int* in_sizes, int n_in,
                              void* d_out, int out_size, void* d_ws, size_t ws_size,
                              hipStream_t stream) {
    const float* inp = (const float*)d_in[0];
    const float* adj = (const float*)d_in[1];
    const float* W   = (const float*)d_in[2];
    const float* b   = (const float*)d_in[3];
    float* out = (float*)d_out;

    char*  ws = (char*)d_ws;
    const size_t HP = (size_t)N_NODES * F_DIM * sizeof(short);   // 2 MB packed bf16 h
    short* hpack = (short*)ws;
    float* partial = (float*)(ws + HP);
    const size_t P1 = (size_t)N_NODES * F_DIM * sizeof(float);   // 4 MB per partial

    dense_h<<<N_NODES / 64, 256, 0, stream>>>(inp, W, hpack);

    if (ws_size >= HP + 8 * P1) {
        dim3 g(N_NODES / 64, 8);
        spmm_adj<<<g, 256, 0, stream>>>(adj, hpack, partial, N_NODES / 8);
        reduce_add<<<(N_NODES * F_DIM) / 1024, 256, 0, stream>>>(partial, b, out, 8);
    } else if (ws_size >= HP + P1) {
        dim3 g(N_NODES / 64, 1);
        spmm_adj<<<g, 256, 0, stream>>>(adj, hpack, partial, N_NODES);
        reduce_add<<<(N_NODES * F_DIM) / 1024, 256, 0, stream>>>(partial, b, out, 1);
    } else {
        dim3 g(N_NODES / 64, 1);
        spmm_adj<<<g, 256, 0, stream>>>(adj, hpack, out, N_NODES);
        reduce_add<<<(N_NODES * F_DIM) / 1024, 256, 0, stream>>>(out, b, out, 1);
    }
}

// Round 3
// 229.385 us; speedup vs baseline: 1.4975x; 1.4975x over previous
//
#include <hip/hip_runtime.h>
#include <hip/hip_bf16.h>
#include <stdint.h>

typedef __attribute__((ext_vector_type(4))) float f32x4;
typedef __attribute__((ext_vector_type(8))) __bf16 bf16x8;
typedef __attribute__((ext_vector_type(2))) unsigned int u32x2;
typedef __attribute__((ext_vector_type(4))) unsigned int u32x4;

#define N_NODES 16384
#define F_DIM   64

__device__ inline unsigned cvtpk_bf16(float lo, float hi) {
    unsigned r;
    asm("v_cvt_pk_bf16_f32 %0, %1, %2" : "=v"(r) : "v"(lo), "v"(hi));
    return r;
}

// ---------------------------------------------------------------------------
// Kernel A: h = input @ W (fp32 compute), stored bf16 in MFMA B-frag layout:
// chunk[(kb*4+ct)*64 + l] (16B) = h[kb*32 + (l>>4)*8 + j][ct*16 + (l&15)]
// ---------------------------------------------------------------------------
__global__ __launch_bounds__(256) void dense_h(const float* __restrict__ inp,
                                               const float* __restrict__ W,
                                               short* __restrict__ hpack) {
    __shared__ float in_lds[64][64];
    __shared__ float wt_lds[64][68];
    const int t = threadIdx.x;
    const int blk = blockIdx.x;

#pragma unroll
    for (int i = 0; i < 4; ++i) {
        int n = i * 256 + t; int row = n >> 4; int c = n & 15;
        f32x4 v = *(const f32x4*)(inp + (size_t)(blk * 64 + row) * 64 + c * 4);
        *(f32x4*)(&in_lds[row][c * 4]) = v;
    }
#pragma unroll
    for (int i = 0; i < 4; ++i) {
        int n = i * 256 + t; int k = n >> 4; int c = n & 15;
        f32x4 v = *(const f32x4*)(W + k * 64 + c * 4);
        wt_lds[c * 4 + 0][k] = v.x; wt_lds[c * 4 + 1][k] = v.y;
        wt_lds[c * 4 + 2][k] = v.z; wt_lds[c * 4 + 3][k] = v.w;
    }
    __syncthreads();

#pragma unroll
    for (int cc = 0; cc < 2; ++cc) {
        int c = cc * 256 + t;
        int kbL = c >> 8; int ct = (c >> 6) & 3; int l = c & 63;
        int f  = ct * 16 + (l & 15);
        int r0 = kbL * 32 + (l >> 4) * 8;
        float acc[8] = {0, 0, 0, 0, 0, 0, 0, 0};
        for (int k = 0; k < 64; k += 4) {
            f32x4 wv = *(const f32x4*)(&wt_lds[f][k]);
#pragma unroll
            for (int j = 0; j < 8; ++j) {
                f32x4 iv = *(const f32x4*)(&in_lds[r0 + j][k]);
                acc[j] += iv.x * wv.x + iv.y * wv.y + iv.z * wv.z + iv.w * wv.w;
            }
        }
        u32x4 w4 = {cvtpk_bf16(acc[0], acc[1]), cvtpk_bf16(acc[2], acc[3]),
                    cvtpk_bf16(acc[4], acc[5]), cvtpk_bf16(acc[6], acc[7])};
        int kb = blk * 2 + kbL;
        *(u32x4*)(hpack + ((size_t)(kb * 4 + ct) * 64 + l) * 8) = w4;
    }
}

// ---------------------------------------------------------------------------
// Kernel B: partial[sp] = adj[:, k-range] @ h[k-range, :]
// R0 structure (coalesced LDS A-staging, 4 waves, raw barrier) + fully
// counted waits: B reg-double-buffered (consumed 2 iters after issue),
// A global loads 2-deep (stA consumes a tile issued one full iter earlier
// -> vmcnt(12), never vmcnt(0) in the loop).
// ---------------------------------------------------------------------------
__global__ __launch_bounds__(256, 2) void spmm_adj(const float* __restrict__ adj,
                                                   const short* __restrict__ hp,
                                                   float* __restrict__ out,
                                                   int kspan) {
    const int rb = blockIdx.x;
    const int sp = blockIdx.y;
    const int k0 = sp * kspan;
    const int iters = kspan >> 6;          // K-step 64; iters even, >= 4
    const int t  = threadIdx.x;
    const int wv = t >> 6;
    const int ln = t & 63;

    __shared__ short At[2][64 * 64];       // bf16, XOR-swizzled, 8KB each

    const size_t rowbase = (size_t)(rb * 64) * N_NODES;

    auto ldA = [&](int tt, f32x4* rv) {
        const float* base = adj + rowbase + (size_t)(k0 + tt * 64);
#pragma unroll
        for (int i = 0; i < 4; ++i) {      // 16 lanes cover 256B contiguous of one row
            int row = i * 16 + (t >> 4); int c = t & 15;
            rv[i] = __builtin_nontemporal_load((const f32x4*)(base + (size_t)row * N_NODES + c * 4));
        }
    };
    auto stA = [&](int buf, const f32x4* rv) {
#pragma unroll
        for (int i = 0; i < 4; ++i) {
            int row = i * 16 + (t >> 4); int c = t & 15;
            u32x2 w = {cvtpk_bf16(rv[i].x, rv[i].y), cvtpk_bf16(rv[i].z, rv[i].w)};
            int byte = row * 128 + ((c * 8) ^ ((row & 7) << 4));
            *(u32x2*)((char*)At[buf] + byte) = w;
        }
    };
    auto ldB = [&](int tt, bf16x8* b) {
        const short* h = hp + (size_t)(k0 >> 5) * 2048 + (size_t)tt * 4096 + ln * 8;
#pragma unroll
        for (int ks2 = 0; ks2 < 2; ++ks2)
#pragma unroll
            for (int ct = 0; ct < 4; ++ct)
                b[ks2 * 4 + ct] = *(const bf16x8*)(h + ks2 * 2048 + ct * 512);
    };

    f32x4 acc[4] = {{0,0,0,0},{0,0,0,0},{0,0,0,0},{0,0,0,0}};
    const int abase = (wv * 16 + (ln & 15)) * 128;
    const int axor  = (ln & 7) << 4;
    const int koff  = (ln >> 4) * 16;

    auto mfmaPhase = [&](int buf, const bf16x8* b) {
#pragma unroll
        for (int ks2 = 0; ks2 < 2; ++ks2) {
            bf16x8 a = *(const bf16x8*)((const char*)At[buf] + abase + ((ks2 * 64 + koff) ^ axor));
#pragma unroll
            for (int ct = 0; ct < 4; ++ct)
                acc[ct] = __builtin_amdgcn_mfma_f32_16x16x32_bf16(a, b[ks2 * 4 + ct], acc[ct], 0, 0, 0);
        }
    };

    f32x4 rvA[4], rvB[4];
    bf16x8 bbA[8], bbB[8];

    // prologue: issue order [B0, A0, B1, A1]; stA(A0) waits vmcnt(12)
    ldB(0, bbA);
    ldA(0, rvA);
    ldB(1, bbB);
    ldA(1, rvB);
    stA(0, rvA);
    asm volatile("s_waitcnt lgkmcnt(0)" ::: "memory");
    __builtin_amdgcn_s_barrier();

    int tt = 0;
    for (; tt + 2 < iters; tt += 2) {
        // even iter: compute A(tt)[buf0] x B(tt); issue B(tt+2),A(tt+2); store A(tt+1)->buf1
        mfmaPhase(0, bbA);
        ldB(tt + 2, bbA);
        ldA(tt + 2, rvA);
        __builtin_amdgcn_sched_barrier(0);   // pin: issues before the stA vmcnt wait
        stA(1, rvB);                          // consumes A(tt+1), issued one iter ago -> vmcnt(12)
        asm volatile("s_waitcnt lgkmcnt(0)" ::: "memory");
        __builtin_amdgcn_s_barrier();
        // odd iter
        mfmaPhase(1, bbB);
        ldB(tt + 3, bbB);
        ldA(tt + 3, rvB);
        __builtin_amdgcn_sched_barrier(0);
        stA(0, rvA);                          // consumes A(tt+2) -> vmcnt(12)
        asm volatile("s_waitcnt lgkmcnt(0)" ::: "memory");
        __builtin_amdgcn_s_barrier();
    }
    // tail: tt == iters-2
    mfmaPhase(0, bbA);
    stA(1, rvB);
    asm volatile("s_waitcnt lgkmcnt(0)" ::: "memory");
    __builtin_amdgcn_s_barrier();
    mfmaPhase(1, bbB);

    // epilogue: C layout col=lane&15, row=(lane>>4)*4+j
    float* o = out + (size_t)sp * ((size_t)N_NODES * F_DIM);
    const int orow0 = rb * 64 + wv * 16 + (ln >> 4) * 4;
    const int col   = ln & 15;
#pragma unroll
    for (int ct = 0; ct < 4; ++ct)
#pragma unroll
        for (int j = 0; j < 4; ++j)
            o[(size_t)(orow0 + j) * F_DIM + ct * 16 + col] = acc[ct][j];
}

// ---------------------------------------------------------------------------
// Kernel C: out = sum_i partial[i] + bias
// ---------------------------------------------------------------------------
__global__ __launch_bounds__(256) void reduce_add(const float* __restrict__ part,
                                                  const float* __restrict__ bias,
                                                  float* __restrict__ out, int nsp) {
    int g = blockIdx.x * 256 + threadIdx.x;
    f32x4 s = {0, 0, 0, 0};
    for (int i = 0; i < nsp; ++i)
        s += *(const f32x4*)(part + (size_t)i * ((size_t)N_NODES * F_DIM) + (size_t)g * 4);
    f32x4 bv = *(const f32x4*)(bias + ((g * 4) & 63));
    *(f32x4*)(out + (size_t)g * 4) = s + bv;
}

extern "C" void kernel_launch(void* const* d_in, const int* in_sizes, int n_in,
                              void* d_out, int out_size, void* d_ws, size_t ws_size,
                              hipStream_t stream) {
    const float* inp = (const float*)d_in[0];
    const float* adj = (const float*)d_in[1];
    const float* W   = (const float*)d_in[2];
    const float* b   = (const float*)d_in[3];
    float* out = (float*)d_out;

    char*  ws = (char*)d_ws;
    const size_t HP = (size_t)N_NODES * F_DIM * sizeof(short);   // 2 MB packed bf16 h
    short* hpack = (short*)ws;
    float* partial = (float*)(ws + HP);
    const size_t P1 = (size_t)N_NODES * F_DIM * sizeof(float);   // 4 MB per partial

    dense_h<<<N_NODES / 64, 256, 0, stream>>>(inp, W, hpack);

    if (ws_size >= HP + 4 * P1) {
        dim3 g(N_NODES / 64, 4);
        spmm_adj<<<g, 256, 0, stream>>>(adj, hpack, partial, N_NODES / 4);
        reduce_add<<<(N_NODES * F_DIM) / 1024, 256, 0, stream>>>(partial, b, out, 4);
    } else if (ws_size >= HP + P1) {
        dim3 g(N_NODES / 64, 1);
        spmm_adj<<<g, 256, 0, stream>>>(adj, hpack, partial, N_NODES);
        reduce_add<<<(N_NODES * F_DIM) / 1024, 256, 0, stream>>>(partial, b, out, 1);
    } else {
        dim3 g(N_NODES / 64, 1);
        spmm_adj<<<g, 256, 0, stream>>>(adj, hpack, out, N_NODES);
        reduce_add<<<(N_NODES * F_DIM) / 1024, 256, 0, stream>>>(out, b, out, 1);
    }
}